// Round 3
// baseline (968.639 us; speedup 1.0000x reference)
//
#include <hip/hip_runtime.h>
#include <hip/hip_bf16.h>

// Problem: B=2, S=2048, HID=1024, NH=16, HD=64. fp32 in/out.
// d_out = [out (2*2048*1024) | attn (2*16*2048*2048)] fp32.
#define BB   2
#define SS   2048
#define HID  1024
#define NH   16
#define HD   64
#define NEGS -30000.0f

typedef __bf16 bf16x8 __attribute__((ext_vector_type(8)));
typedef float  f32x4  __attribute__((ext_vector_type(4)));

static __device__ __forceinline__ f32x4 mfma_bf16(bf16x8 a, bf16x8 b, f32x4 c) {
    return __builtin_amdgcn_mfma_f32_16x16x32_bf16(a, b, c, 0, 0, 0);
}

static __device__ __forceinline__ void split_bf16(float f, __bf16* hp, __bf16* lp) {
    __bf16 h = (__bf16)f;
    *hp = h;
    *lp = (__bf16)(f - (float)h);
}

static __device__ __forceinline__ float clampf(float v, float lo, float hi) {
    return fminf(fmaxf(v, lo), hi);   // scrubs NaN -> lo
}

// ---------------------------------------------------------------------------
// K0: pre-split Wq, Wk (fp32 -> bf16 hi/lo). 1024 x 256 threads, 4 elems each.
// ---------------------------------------------------------------------------
__global__ __launch_bounds__(256) void wsplit_kernel(
    const float* __restrict__ Wq, const float* __restrict__ Wk,
    __bf16* __restrict__ wqh, __bf16* __restrict__ wql,
    __bf16* __restrict__ wkh, __bf16* __restrict__ wkl)
{
    const size_t o = ((size_t)blockIdx.x * 256 + threadIdx.x) * 4;
    float4 q = *(const float4*)&Wq[o];
    float4 k = *(const float4*)&Wk[o];
    __bf16 qhv[4], qlv[4], khv[4], klv[4];
    split_bf16(q.x, &qhv[0], &qlv[0]); split_bf16(q.y, &qhv[1], &qlv[1]);
    split_bf16(q.z, &qhv[2], &qlv[2]); split_bf16(q.w, &qhv[3], &qlv[3]);
    split_bf16(k.x, &khv[0], &klv[0]); split_bf16(k.y, &khv[1], &klv[1]);
    split_bf16(k.z, &khv[2], &klv[2]); split_bf16(k.w, &khv[3], &klv[3]);
    *(uint2*)&wqh[o] = *(uint2*)qhv;
    *(uint2*)&wql[o] = *(uint2*)qlv;
    *(uint2*)&wkh[o] = *(uint2*)khv;
    *(uint2*)&wkl[o] = *(uint2*)klv;
}

// ---------------------------------------------------------------------------
// K1: fused QKV projection, 2 heads (128 output cols) per block.
// x split hi/lo in-LDS once per block (amortized over Q,K,V and 2 heads).
// Wq/Wk pre-split (bf16), Wv converted inline.
// qh/ql = hi/lo of 8*(x@Wq^T+bq) [bh][s][d]; kh/kl = hi/lo of x@Wk^T+bk;
// vt = bf16(x@Wv^T+bv) transposed [bh][d][s].
// ---------------------------------------------------------------------------
#define AH_O   0
#define AL_O   2560
#define BQH_O  5120
#define BQL_O  10240
#define BKH_O  15360
#define BKL_O  20480
#define BVH_O  25600

__global__ __launch_bounds__(256) void qkv_kernel(
    const float* __restrict__ x,
    const __bf16* __restrict__ wqh, const __bf16* __restrict__ wql,
    const __bf16* __restrict__ wkh, const __bf16* __restrict__ wkl,
    const float* __restrict__ Wv,
    const float* __restrict__ bq, const float* __restrict__ bk,
    const float* __restrict__ bv,
    __bf16* __restrict__ qh, __bf16* __restrict__ ql,
    __bf16* __restrict__ kh, __bf16* __restrict__ kl,
    __bf16* __restrict__ vt)
{
    __shared__ __align__(16) __bf16 SM[30720];   // 61.4 KB

    const int hp = blockIdx.x;            // 0..7 (head pair)
    const int mt = blockIdx.y;            // 0..63 (token tile)
    const int o0 = hp * 128;

    const int tid  = threadIdx.x;
    const int wave = tid >> 6, lane = tid & 63;
    const int l16  = lane & 15, quad = lane >> 4;

    const f32x4 zero4 = {0.f, 0.f, 0.f, 0.f};
    f32x4 aq[8], ak[8], av[8];
#pragma unroll
    for (int c = 0; c < 8; c++) { aq[c] = zero4; ak[c] = zero4; av[c] = zero4; }

    const int arow = tid >> 2, ac4 = tid & 3;          // A: 8 fp32 / thread
    const size_t xoff = (size_t)(mt * 64 + arow) * HID + ac4 * 8;

    for (int k0 = 0; k0 < HID; k0 += 32) {
        __syncthreads();
        // ---- stage A (x tile, split) ----
        {
            float4 a0 = *(const float4*)&x[xoff + k0];
            float4 a1 = *(const float4*)&x[xoff + k0 + 4];
            __bf16 hh[8], ll[8];
            split_bf16(a0.x, &hh[0], &ll[0]); split_bf16(a0.y, &hh[1], &ll[1]);
            split_bf16(a0.z, &hh[2], &ll[2]); split_bf16(a0.w, &hh[3], &ll[3]);
            split_bf16(a1.x, &hh[4], &ll[4]); split_bf16(a1.y, &hh[5], &ll[5]);
            split_bf16(a1.z, &hh[6], &ll[6]); split_bf16(a1.w, &hh[7], &ll[7]);
            const int ldst = arow * 40 + ac4 * 8;
            *(uint4*)&SM[AH_O + ldst] = *(uint4*)hh;
            *(uint4*)&SM[AL_O + ldst] = *(uint4*)ll;
        }
        // ---- stage B tiles (128 rows x 32 k) ----
#pragma unroll
        for (int j = 0; j < 2; j++) {
            const int bidx = tid + j * 256;            // 0..511
            const int brow = bidx >> 2, bc4 = bidx & 3;
            const size_t so = (size_t)(o0 + brow) * HID + k0 + bc4 * 8;
            const int ldst = brow * 40 + bc4 * 8;
            *(uint4*)&SM[BQH_O + ldst] = *(const uint4*)&wqh[so];
            *(uint4*)&SM[BQL_O + ldst] = *(const uint4*)&wql[so];
            *(uint4*)&SM[BKH_O + ldst] = *(const uint4*)&wkh[so];
            *(uint4*)&SM[BKL_O + ldst] = *(const uint4*)&wkl[so];
            float4 v0 = *(const float4*)&Wv[so];
            float4 v1 = *(const float4*)&Wv[so + 4];
            __bf16 vh[8];
            vh[0] = (__bf16)v0.x; vh[1] = (__bf16)v0.y;
            vh[2] = (__bf16)v0.z; vh[3] = (__bf16)v0.w;
            vh[4] = (__bf16)v1.x; vh[5] = (__bf16)v1.y;
            vh[6] = (__bf16)v1.z; vh[7] = (__bf16)v1.w;
            *(uint4*)&SM[BVH_O + ldst] = *(uint4*)vh;
        }
        __syncthreads();

        const int aoff = (wave * 16 + l16) * 40 + quad * 8;
        bf16x8 aH = *(const bf16x8*)&SM[AH_O + aoff];
        bf16x8 aL = *(const bf16x8*)&SM[AL_O + aoff];
#pragma unroll
        for (int c = 0; c < 8; c++) {
            const int boff = (c * 16 + l16) * 40 + quad * 8;
            bf16x8 bH = *(const bf16x8*)&SM[BQH_O + boff];
            bf16x8 bL = *(const bf16x8*)&SM[BQL_O + boff];
            aq[c] = mfma_bf16(aH, bH, aq[c]);
            aq[c] = mfma_bf16(aH, bL, aq[c]);
            aq[c] = mfma_bf16(aL, bH, aq[c]);
            bH = *(const bf16x8*)&SM[BKH_O + boff];
            bL = *(const bf16x8*)&SM[BKL_O + boff];
            ak[c] = mfma_bf16(aH, bH, ak[c]);
            ak[c] = mfma_bf16(aH, bL, ak[c]);
            ak[c] = mfma_bf16(aL, bH, ak[c]);
            bH = *(const bf16x8*)&SM[BVH_O + boff];
            av[c] = mfma_bf16(aH, bH, av[c]);
        }
    }

    const int t0 = mt * 64;
    const int bb = t0 >> 11;              // batch
    const int s0 = t0 & (SS - 1);

    // ---- Q/K epilogue ----
#pragma unroll
    for (int c = 0; c < 8; c++) {
        const int og   = o0 + c * 16 + l16;   // global output col
        const int head = og >> 6;
        const int d    = og & 63;
        const float bqv = bq[og];
        const float bkv = bk[og];
#pragma unroll
        for (int r = 0; r < 4; r++) {
            const int srow = s0 + wave * 16 + quad * 4 + r;
            const size_t o = ((size_t)(bb * NH + head) * SS + srow) * HD + d;
            float vq = clampf((aq[c][r] + bqv) * 8.0f, -1e4f, 1e4f);
            __bf16 hv, lv;
            split_bf16(vq, &hv, &lv);
            qh[o] = hv; ql[o] = lv;
            float vk = clampf(ak[c][r] + bkv, -1e4f, 1e4f);
            split_bf16(vk, &hv, &lv);
            kh[o] = hv; kl[o] = lv;
        }
    }

    // ---- V transpose epilogue (reuse SM as [128][72]) ----
    __syncthreads();
#pragma unroll
    for (int c = 0; c < 8; c++) {
        const int col = c * 16 + l16;         // 0..127
        const float bvv = bv[o0 + col];
#pragma unroll
        for (int r = 0; r < 4; r++)
            SM[col * 72 + wave * 16 + quad * 4 + r] =
                (__bf16)clampf(av[c][r] + bvv, -1e4f, 1e4f);
    }
    __syncthreads();
#pragma unroll
    for (int i = 0; i < 4; i++) {
        const int idx = tid + i * 256;        // 0..1023
        const int col = idx >> 3, c8 = idx & 7;
        const int head = col >> 6, d = col & 63;
        const size_t o = ((size_t)(bb * NH + hp * 2 + head) * HD + d) * SS + s0 + c8 * 8;
        *(uint4*)&vt[o] = *(const uint4*)&SM[col * 72 + c8 * 8];
    }
}

// ---------------------------------------------------------------------------
// K2: single-pass flash attention. Block = (bh, 64-row q-tile), qt descending.
// Stores raw scores s (fp32) to attn during the pass; in-block epilogue
// rescales to exp(s-m)/l and zero-fills the upper triangle.
// ---------------------------------------------------------------------------
__global__ __launch_bounds__(256) void attn_kernel(
    const __bf16* __restrict__ qh, const __bf16* __restrict__ ql,
    const __bf16* __restrict__ kh, const __bf16* __restrict__ kl,
    const __bf16* __restrict__ vt,
    float* __restrict__ attn, __bf16* __restrict__ ctx)
{
    __shared__ __align__(16) __bf16 Qh[64][72], Ql[64][72];
    __shared__ __align__(16) __bf16 Kh[64][72], Kl[64][72];
    __shared__ __align__(16) __bf16 Vt[64][72], Ps[64][72];
    __shared__ float m_sh[64], il_sh[64];

    const int bid = blockIdx.x;
    const int qt = 31 - (bid >> 5);       // heavy blocks first
    const int bh = bid & 31;
    const int b = bh >> 4, h = bh & 15;

    const int tid  = threadIdx.x;
    const int wave = tid >> 6, lane = tid & 63;
    const int l16  = lane & 15, quad = lane >> 4;

    {
        const size_t base = ((size_t)bh * SS + qt * 64) * HD;
#pragma unroll
        for (int i = 0; i < 2; i++) {
            const int idx = tid + i * 256;
            const int row = idx >> 3, c8 = idx & 7;
            *(uint4*)&Qh[row][c8 * 8] = *(const uint4*)&qh[base + row * HD + c8 * 8];
            *(uint4*)&Ql[row][c8 * 8] = *(const uint4*)&ql[base + row * HD + c8 * 8];
        }
    }

    float m4[4], l4[4];
#pragma unroll
    for (int r = 0; r < 4; r++) { m4[r] = -1e30f; l4[r] = 0.f; }

    const f32x4 zero4 = {0.f, 0.f, 0.f, 0.f};
    f32x4 cacc[4] = {zero4, zero4, zero4, zero4};

    const size_t srow_base = (size_t)bh * SS + qt * 64;

    for (int kt = 0; kt <= qt; kt++) {
        __syncthreads();
        const size_t kbase = ((size_t)bh * SS + kt * 64) * HD;
        const size_t vbase = (size_t)bh * HD * SS + kt * 64;
#pragma unroll
        for (int i = 0; i < 2; i++) {
            const int idx = tid + i * 256;
            const int row = idx >> 3, c8 = idx & 7;
            *(uint4*)&Kh[row][c8 * 8] = *(const uint4*)&kh[kbase + row * HD + c8 * 8];
            *(uint4*)&Kl[row][c8 * 8] = *(const uint4*)&kl[kbase + row * HD + c8 * 8];
            *(uint4*)&Vt[row][c8 * 8] = *(const uint4*)&vt[vbase + (size_t)row * SS + c8 * 8];
        }
        __syncthreads();

        f32x4 sacc[4] = {zero4, zero4, zero4, zero4};
#pragma unroll
        for (int ks = 0; ks < 2; ks++) {
            bf16x8 aH = *(const bf16x8*)&Qh[wave * 16 + l16][ks * 32 + quad * 8];
            bf16x8 aL = *(const bf16x8*)&Ql[wave * 16 + l16][ks * 32 + quad * 8];
#pragma unroll
            for (int c = 0; c < 4; c++) {
                bf16x8 bH = *(const bf16x8*)&Kh[c * 16 + l16][ks * 32 + quad * 8];
                bf16x8 bL = *(const bf16x8*)&Kl[c * 16 + l16][ks * 32 + quad * 8];
                sacc[c] = mfma_bf16(aH, bH, sacc[c]);
                sacc[c] = mfma_bf16(aH, bL, sacc[c]);
                sacc[c] = mfma_bf16(aL, bH, sacc[c]);
            }
        }
        if (kt == qt) {                        // causal mask on diagonal tile
#pragma unroll
            for (int c = 0; c < 4; c++) {
                const int col = c * 16 + l16;
#pragma unroll
                for (int r = 0; r < 4; r++)
                    if (col > wave * 16 + quad * 4 + r) sacc[c][r] = NEGS;
            }
        }
        // raw score store (fp32), C-layout scatter: 4x64B segments / instr
#pragma unroll
        for (int c = 0; c < 4; c++) {
#pragma unroll
            for (int r = 0; r < 4; r++) {
                const size_t o = (srow_base + wave * 16 + quad * 4 + r) * SS
                               + kt * 64 + c * 16 + l16;
                attn[o] = sacc[c][r];
            }
        }
        // online softmax update + P (unnormalized) to LDS (wave-private rows)
#pragma unroll
        for (int r = 0; r < 4; r++) {
            float mx = fmaxf(fmaxf(sacc[0][r], sacc[1][r]), fmaxf(sacc[2][r], sacc[3][r]));
#pragma unroll
            for (int off = 1; off < 16; off <<= 1) mx = fmaxf(mx, __shfl_xor(mx, off));
            const float mn = fmaxf(m4[r], mx);
            const float p0 = __expf(sacc[0][r] - mn);
            const float p1 = __expf(sacc[1][r] - mn);
            const float p2 = __expf(sacc[2][r] - mn);
            const float p3 = __expf(sacc[3][r] - mn);
            float se = p0 + p1 + p2 + p3;
#pragma unroll
            for (int off = 1; off < 16; off <<= 1) se += __shfl_xor(se, off);
            const float alpha = __expf(m4[r] - mn);
            l4[r] = l4[r] * alpha + se;
            m4[r] = mn;
#pragma unroll
            for (int dt = 0; dt < 4; dt++) cacc[dt][r] *= alpha;
            const int rr = wave * 16 + quad * 4 + r;
            Ps[rr][l16]      = (__bf16)p0;
            Ps[rr][16 + l16] = (__bf16)p1;
            Ps[rr][32 + l16] = (__bf16)p2;
            Ps[rr][48 + l16] = (__bf16)p3;
        }
        // PV (no barrier: Ps rows are wave-private)
#pragma unroll
        for (int ks = 0; ks < 2; ks++) {
            bf16x8 ap = *(const bf16x8*)&Ps[wave * 16 + l16][ks * 32 + quad * 8];
#pragma unroll
            for (int dt = 0; dt < 4; dt++) {
                bf16x8 bv8 = *(const bf16x8*)&Vt[dt * 16 + l16][ks * 32 + quad * 8];
                cacc[dt] = mfma_bf16(ap, bv8, cacc[dt]);
            }
        }
    }

    // ---- publish final stats ----
    float il[4];
#pragma unroll
    for (int r = 0; r < 4; r++) il[r] = (l4[r] > 0.f) ? (1.0f / l4[r]) : 0.f;
    if (l16 == 0) {
#pragma unroll
        for (int r = 0; r < 4; r++) {
            m_sh[wave * 16 + quad * 4 + r]  = m4[r];
            il_sh[wave * 16 + quad * 4 + r] = il[r];
        }
    }
    __syncthreads();   // also drains the raw-s global writes (vmcnt(0) at barrier)

    // ---- rescale pass: attn = exp(s - m) * il ----
    for (int kt = 0; kt <= qt; kt++) {
#pragma unroll
        for (int i = 0; i < 4; i++) {
            const int idx = tid + i * 256;          // 1024 float4 per tile
            const int row = idx >> 4, c4 = idx & 15;
            const size_t o = (srow_base + row) * SS + kt * 64 + c4 * 4;
            float4 v = *(const float4*)&attn[o];
            const float mm = m_sh[row], ii = il_sh[row];
            v.x = __expf(v.x - mm) * ii;
            v.y = __expf(v.y - mm) * ii;
            v.z = __expf(v.z - mm) * ii;
            v.w = __expf(v.w - mm) * ii;
            *(float4*)&attn[o] = v;
        }
    }
    // ---- zero-fill upper-triangle tiles ----
    const float4 zf4 = {0.f, 0.f, 0.f, 0.f};
    for (int kt = qt + 1; kt < SS / 64; kt++) {
#pragma unroll
        for (int i = 0; i < 4; i++) {
            const int idx = tid + i * 256;
            const int row = idx >> 4, c4 = idx & 15;
            const size_t o = (srow_base + row) * SS + kt * 64 + c4 * 4;
            *(float4*)&attn[o] = zf4;
        }
    }

    // ---- ctx epilogue: [b][s][h*64+d] bf16 ----
#pragma unroll
    for (int dt = 0; dt < 4; dt++) {
        const int d = dt * 16 + l16;
#pragma unroll
        for (int r = 0; r < 4; r++) {
            const int srow = qt * 64 + wave * 16 + quad * 4 + r;
            ctx[(size_t)(b * SS + srow) * HID + h * 64 + d] =
                (__bf16)clampf(cacc[dt][r] * il[r], -1e4f, 1e4f);
        }
    }
}

// ---------------------------------------------------------------------------
// K3: out = ctx @ Wo^T + bo   (ctx bf16 in ws, Wo fp32 -> bf16-hi inline)
// ---------------------------------------------------------------------------
__global__ __launch_bounds__(256) void out_kernel(
    const __bf16* __restrict__ ctx, const float* __restrict__ Wo,
    const float* __restrict__ bo, float* __restrict__ out)
{
    __shared__ __align__(16) __bf16 As[64][40];
    __shared__ __align__(16) __bf16 Bs[64][40];

    const int nt = blockIdx.x;   // 0..15
    const int mt = blockIdx.y;   // 0..63
    const int o0 = nt * 64;

    const int tid  = threadIdx.x;
    const int wave = tid >> 6, lane = tid & 63;
    const int l16  = lane & 15, quad = lane >> 4;

    const f32x4 zero4 = {0.f, 0.f, 0.f, 0.f};
    f32x4 acc[4] = {zero4, zero4, zero4, zero4};

    const int arow = tid >> 2, ac4 = tid & 3;
    const size_t aoff = (size_t)(mt * 64 + arow) * HID + ac4 * 8;
    const size_t woff = (size_t)(o0 + arow) * HID + ac4 * 8;

    for (int k0 = 0; k0 < HID; k0 += 32) {
        __syncthreads();
        *(uint4*)&As[arow][ac4 * 8] = *(const uint4*)&ctx[aoff + k0];
        float4 b0 = *(const float4*)&Wo[woff + k0];
        float4 b1 = *(const float4*)&Wo[woff + k0 + 4];
        __bf16 bh8[8];
        bh8[0] = (__bf16)b0.x; bh8[1] = (__bf16)b0.y;
        bh8[2] = (__bf16)b0.z; bh8[3] = (__bf16)b0.w;
        bh8[4] = (__bf16)b1.x; bh8[5] = (__bf16)b1.y;
        bh8[6] = (__bf16)b1.z; bh8[7] = (__bf16)b1.w;
        *(uint4*)&Bs[arow][ac4 * 8] = *(uint4*)bh8;
        __syncthreads();
        bf16x8 a = *(const bf16x8*)&As[wave * 16 + l16][quad * 8];
#pragma unroll
        for (int c = 0; c < 4; c++) {
            bf16x8 b = *(const bf16x8*)&Bs[c * 16 + l16][quad * 8];
            acc[c] = mfma_bf16(a, b, acc[c]);
        }
    }

#pragma unroll
    for (int c = 0; c < 4; c++) {
        const int d = o0 + c * 16 + l16;
        const float bias = bo[d];
#pragma unroll
        for (int r = 0; r < 4; r++) {
            const int t = mt * 64 + wave * 16 + quad * 4 + r;
            out[(size_t)t * HID + d] = clampf(acc[c][r] + bias, -1e4f, 1e4f);
        }
    }
}

extern "C" void kernel_launch(void* const* d_in, const int* in_sizes, int n_in,
                              void* d_out, int out_size, void* d_ws, size_t ws_size,
                              hipStream_t stream) {
    const float* x  = (const float*)d_in[0];
    const float* Wq = (const float*)d_in[1];
    const float* bq = (const float*)d_in[2];
    const float* Wk = (const float*)d_in[3];
    const float* bk = (const float*)d_in[4];
    const float* Wv = (const float*)d_in[5];
    const float* bv = (const float*)d_in[6];
    const float* Wo = (const float*)d_in[7];
    const float* bo = (const float*)d_in[8];

    float* out  = (float*)d_out;
    float* attn = out + (size_t)BB * SS * HID;

    const size_t NQ = (size_t)BB * NH * SS * HD;   // 4,194,304
    const size_t NW = (size_t)HID * HID;           // 1,048,576
    __bf16* ws  = (__bf16*)d_ws;
    __bf16* qh  = ws;                 // [0,  NQ)
    __bf16* ql  = qh + NQ;            // [NQ, 2NQ)
    __bf16* kh  = ql + NQ;
    __bf16* kl  = kh + NQ;
    __bf16* vt  = kl + NQ;
    __bf16* wqh = vt + NQ;            // weight splits: 4*NW = NQ elems
    __bf16* wql = wqh + NW;
    __bf16* wkh = wql + NW;
    __bf16* wkl = wkh + NW;
    __bf16* ctx = wqh;                // aliases dead weight splits after K1
    // total: 6*NQ*2B = 48 MiB (same footprint as the proven round-2 layout)

    wsplit_kernel<<<dim3(1024), 256, 0, stream>>>(Wq, Wk, wqh, wql, wkh, wkl);
    qkv_kernel<<<dim3(8, 64), 256, 0, stream>>>(x, wqh, wql, wkh, wkl, Wv,
                                                bq, bk, bv, qh, ql, kh, kl, vt);
    attn_kernel<<<dim3(1024), 256, 0, stream>>>(qh, ql, kh, kl, vt, attn, ctx);
    out_kernel<<<dim3(16, 64), 256, 0, stream>>>(ctx, Wo, bo, out);
}